// Round 1
// baseline (17266.565 us; speedup 1.0000x reference)
//
#include <hip/hip_runtime.h>
#include <hip/hip_bf16.h>

// ---------------- architecture constants ----------------
namespace {
constexpr int Bz  = 4;      // batch
constexpr int Sq  = 256;    // seq len
constexpr int Dm  = 512;    // d_model
constexpr int NHd = 8;      // heads
constexpr int Tw  = 65;     // window (1 ssm + 64 input)
constexpr int DFFc= 2048;   // ffn hidden
constexpr int Vc  = 32000;  // vocab
constexpr int DKc = 64;     // pool key dim
constexpr int DIc = 1024;   // ssm d_inner
constexpr int DSc = 16;     // ssm d_state
constexpr int NWc = Bz*Sq;  // 1024 windows

constexpr int GF_BIAS = 1;
constexpr int GF_GELU = 2;
constexpr int GF_RES  = 4;
constexpr int GF_BT   = 8;
constexpr int GF_SCAT = 16;
}

// ---------------- utility kernels ----------------
__global__ __launch_bounds__(256) void k_zero(float* p, int n) {
  int i = blockIdx.x*256 + threadIdx.x;
  if (i < n) p[i] = 0.f;
}

__global__ __launch_bounds__(256) void k_gather(const int* ids, const float* emb, float* emb_seq) {
  int e = blockIdx.x*256 + threadIdx.x;          // Bz*Sq*Dm total
  int d  = e & (Dm-1);
  int bs = e >> 9;                               // b*Sq + s
  emb_seq[e] = emb[(size_t)ids[bs]*Dm + d];
}

__global__ __launch_bounds__(256) void k_uvec(const float* pool_wk, const float* pool_q, float* u) {
  int d = blockIdx.x*256 + threadIdx.x;
  if (d < Dm) {
    float acc = 0.f;
    for (int e = 0; e < DKc; e++) acc += pool_wk[d*DKc + e]*pool_q[e];
    u[d] = acc;
  }
}

// Precompute pool softmax partials over the 64 input slots for each write step.
__global__ __launch_bounds__(256) void k_poolpre(const float* emb_seq, const float* u,
                                                 float* Pres, float* Zres, float* Mres) {
  int kk = blockIdx.x / Bz + 1;   // 1..15
  int b  = blockIdx.x % Bz;
  int t  = kk*16;
  __shared__ float sj[64];
  __shared__ float ej[64];
  __shared__ float sM;
  int tid = threadIdx.x;
  if (tid < 64) {
    int j = tid + 1;              // window pos 1..64
    int idx = t - 64 + j;
    float s = 0.f;
    if (idx >= 0) {
      const float* row = emb_seq + ((size_t)b*Sq + idx)*Dm;
      float acc = 0.f;
      for (int d = 0; d < Dm; d++) acc += row[d]*u[d];
      s = acc*0.125f;
    }
    sj[tid] = s;
  }
  __syncthreads();
  if (tid == 0) {
    float m = -1e30f;
    for (int j = 0; j < 64; j++) m = fmaxf(m, sj[j]);
    sM = m;
  }
  __syncthreads();
  if (tid < 64) ej[tid] = expf(sj[tid] - sM);
  __syncthreads();
  if (tid == 0) {
    float z = 0.f;
    for (int j = 0; j < 64; j++) z += ej[j];
    Zres[kk*Bz + b] = z;
    Mres[kk*Bz + b] = sM;
  }
  __syncthreads();
  for (int d = tid; d < Dm; d += 256) {
    float acc = 0.f;
    for (int j = 1; j <= 64; j++) {
      int idx = t - 64 + j;
      if (idx >= 0) acc += ej[j-1]*emb_seq[((size_t)b*Sq + idx)*Dm + d];
    }
    Pres[((size_t)kk*Bz + b)*Dm + d] = acc;
  }
}

// ---------------- phase 1: sequential SSM (write steps only) ----------------
// xz = x_in @ ssm_win[l]  -> x1, z.  For layer 0, x_in = pooled (computed here).
__global__ __launch_bounds__(256) void k_ssm_xz(const float* win, const float* ssm_vec,
                                                const float* Pres, const float* Zres, const float* Mres,
                                                const float* u, const float* xb, float* pooled,
                                                float* x1buf, float* zbuf, int kk, int layer) {
  int jg = blockIdx.x;       // 0..31
  int b  = blockIdx.y;
  int tid = threadIdx.x;
  __shared__ float xin[Dm];
  __shared__ float red[256];
  __shared__ float r2[4][64];
  if (layer == 0) {
    const float* sv = ssm_vec + ((size_t)(kk-1)*Bz + b)*Dm;
    float p = 0.f;
    for (int i = tid; i < Dm; i += 256) p += sv[i]*u[i];
    red[tid] = p; __syncthreads();
    for (int s = 128; s > 0; s >>= 1) { if (tid < s) red[tid] += red[tid+s]; __syncthreads(); }
    float s0  = red[0]*0.125f;
    float e0  = expf(s0 - Mres[kk*Bz + b]);
    float inv = 1.f/(e0 + Zres[kk*Bz + b]);
    const float* Pr = Pres + ((size_t)kk*Bz + b)*Dm;
    for (int i = tid; i < Dm; i += 256) {
      float val = (e0*sv[i] + Pr[i])*inv;
      xin[i] = val;
      if (jg == 0) pooled[b*Dm + i] = val;
    }
  } else {
    for (int i = tid; i < Dm; i += 256) xin[i] = xb[b*Dm + i];
  }
  __syncthreads();
  int ks = tid >> 6, jl = tid & 63;
  int j  = jg*64 + jl;                  // 0..2047
  const float* w = win + j;
  float acc = 0.f;
  int k0 = ks*128;
  #pragma unroll 8
  for (int k = k0; k < k0 + 128; k++) acc += xin[k]*w[(size_t)k*(2*DIc)];
  r2[ks][jl] = acc; __syncthreads();
  if (tid < 64) {
    int jj = jg*64 + tid;
    float v = r2[0][tid] + r2[1][tid] + r2[2][tid] + r2[3][tid];
    if (jj < DIc) x1buf[b*DIc + jj] = v;
    else          zbuf[b*DIc + (jj - DIc)] = v;
  }
}

// dt = softplus(x1 @ wdt + bdt); Bm = x1 @ wB; Cm = x1 @ wC
__global__ __launch_bounds__(256) void k_ssm_proj(const float* wdt, const float* bdt,
                                                  const float* wB, const float* wC,
                                                  const float* x1buf, float* dtbuf,
                                                  float* Bmbuf, float* Cmbuf) {
  int bx = blockIdx.x;       // 0..16
  int b  = blockIdx.y;
  int tid = threadIdx.x;
  __shared__ float x1[DIc];
  __shared__ float r2[4][64];
  __shared__ float r3[8][32];
  for (int i = tid; i < DIc; i += 256) x1[i] = x1buf[b*DIc + i];
  __syncthreads();
  if (bx < 16) {
    int ks = tid >> 6, jl = tid & 63;
    int j = bx*64 + jl;
    const float* w = wdt + j;
    float acc = 0.f;
    int k0 = ks*256;
    #pragma unroll 8
    for (int k = k0; k < k0 + 256; k++) acc += x1[k]*w[(size_t)k*DIc];
    r2[ks][jl] = acc; __syncthreads();
    if (tid < 64) {
      int jj = bx*64 + tid;
      float v = r2[0][tid] + r2[1][tid] + r2[2][tid] + r2[3][tid] + bdt[jj];
      dtbuf[b*DIc + jj] = fmaxf(v, 0.f) + log1pf(expf(-fabsf(v)));   // stable softplus
    }
  } else {
    int ks = tid >> 5, jl = tid & 31;
    int s  = jl & 15;
    const float* w = (jl < 16 ? wB : wC) + s;
    float acc = 0.f;
    int k0 = ks*128;
    #pragma unroll 8
    for (int k = k0; k < k0 + 128; k++) acc += x1[k]*w[(size_t)k*DSc];
    r3[ks][jl] = acc; __syncthreads();
    if (tid < 32) {
      float v = 0.f;
      for (int q = 0; q < 8; q++) v += r3[q][tid];
      if (tid < 16) Bmbuf[b*DSc + tid] = v;
      else          Cmbuf[b*DSc + (tid - 16)] = v;
    }
  }
}

// h' = exp(dt*A)h + dt*Bm*x1 ; y = (h'·Cm + D*x1)*silu(z)
__global__ __launch_bounds__(256) void k_ssm_hy(const float* Alog, const float* ssmD,
                                                const float* dtbuf, const float* x1buf,
                                                const float* zbuf, const float* Bmbuf,
                                                const float* Cmbuf, float* hstate, float* ybuf) {
  int g = blockIdx.x*256 + threadIdx.x;   // 0..4095
  int b = g >> 10;
  int d = g & 1023;
  float dt = dtbuf[g];
  float x1 = x1buf[g];
  float z  = zbuf[g];
  float sil = z / (1.f + expf(-z));
  float* h = hstate + ((size_t)b*DIc + d)*DSc;
  const float* Ar = Alog + (size_t)d*DSc;
  float acc = 0.f;
  #pragma unroll
  for (int s = 0; s < DSc; s++) {
    float A  = -expf(Ar[s]);
    float hn = expf(dt*A)*h[s] + dt*Bmbuf[b*DSc + s]*x1;
    h[s] = hn;
    acc += hn*Cmbuf[b*DSc + s];
  }
  ybuf[g] = (acc + ssmD[d]*x1)*sil;
}

// x_out = x_base + y @ wout
__global__ __launch_bounds__(256) void k_ssm_out(const float* wout, const float* ybuf,
                                                 const float* xbase, float* dst) {
  int jg = blockIdx.x;       // 0..7
  int b  = blockIdx.y;
  int tid = threadIdx.x;
  __shared__ float y[DIc];
  __shared__ float r2[4][64];
  for (int i = tid; i < DIc; i += 256) y[i] = ybuf[b*DIc + i];
  __syncthreads();
  int ks = tid >> 6, jl = tid & 63;
  int j = jg*64 + jl;
  const float* w = wout + j;
  float acc = 0.f;
  int k0 = ks*256;
  #pragma unroll 8
  for (int k = k0; k < k0 + 256; k++) acc += y[k]*w[(size_t)k*Dm];
  r2[ks][jl] = acc; __syncthreads();
  if (tid < 64) {
    int jj = jg*64 + tid;
    dst[b*Dm + jj] = xbase[b*Dm + jj] + r2[0][tid] + r2[1][tid] + r2[2][tid] + r2[3][tid];
  }
}

// ---------------- phase 2: parallel transformer over all windows ----------------
__global__ __launch_bounds__(256) void k_build(const float* emb_seq, const float* ssm_vec,
                                               float* xc, int c, int CW) {
  int e = blockIdx.x*256 + threadIdx.x;   // RC*Dm total
  int d = e & (Dm-1);
  int r = e >> 9;
  int wc = r / Tw, p = r % Tw;
  int w  = c*CW + wc;
  int t  = w >> 2, b = w & 3;
  float val;
  if (p == 0) {
    int kused = (t == 0) ? 0 : ((t-1) >> 4);
    val = ssm_vec[((size_t)kused*Bz + b)*Dm + d];
  } else {
    int idx = t - 64 + p;
    val = (idx >= 0) ? emb_seq[((size_t)b*Sq + idx)*Dm + d] : 0.f;
  }
  xc[e] = val;
}

__global__ __launch_bounds__(256) void k_ln(const float* src, float* dst,
                                            const float* g, const float* bb) {
  int r = blockIdx.x;
  int tid = threadIdx.x;
  const float* x = src + (size_t)r*Dm;
  float v0 = x[tid], v1 = x[tid + 256];
  __shared__ float rs[256], rq[256];
  rs[tid] = v0 + v1; rq[tid] = v0*v0 + v1*v1;
  __syncthreads();
  for (int s = 128; s > 0; s >>= 1) {
    if (tid < s) { rs[tid] += rs[tid+s]; rq[tid] += rq[tid+s]; }
    __syncthreads();
  }
  float mu   = rs[0]*(1.f/Dm);
  float var  = rq[0]*(1.f/Dm) - mu*mu;
  float rstd = rsqrtf(var + 1e-5f);
  float* y = dst + (size_t)r*Dm;
  y[tid]       = (v0 - mu)*rstd*g[tid]       + bb[tid];
  y[tid + 256] = (v1 - mu)*rstd*g[tid + 256] + bb[tid + 256];
}

// final LN over last window position only -> yfinal[w]
__global__ __launch_bounds__(256) void k_lnlast(const float* xc, float* yfinal,
                                                const float* g, const float* bb, int c, int CW) {
  int wc = blockIdx.x;
  int r  = wc*Tw + (Tw-1);
  int w  = c*CW + wc;
  int tid = threadIdx.x;
  const float* x = xc + (size_t)r*Dm;
  float v0 = x[tid], v1 = x[tid + 256];
  __shared__ float rs[256], rq[256];
  rs[tid] = v0 + v1; rq[tid] = v0*v0 + v1*v1;
  __syncthreads();
  for (int s = 128; s > 0; s >>= 1) {
    if (tid < s) { rs[tid] += rs[tid+s]; rq[tid] += rq[tid+s]; }
    __syncthreads();
  }
  float mu   = rs[0]*(1.f/Dm);
  float var  = rq[0]*(1.f/Dm) - mu*mu;
  float rstd = rsqrtf(var + 1e-5f);
  float* y = yfinal + (size_t)w*Dm;
  y[tid]       = (v0 - mu)*rstd*g[tid]       + bb[tid];
  y[tid + 256] = (v1 - mu)*rstd*g[tid + 256] + bb[tid + 256];
}

// Generic fp32 GEMM: C[M,N] = A[M,K] @ B[K,N] (or @ Bt[N,K]^T), optional
// bias/gelu/residual, optional scatter of rows into d_out (lm_head).
__global__ __launch_bounds__(256) void k_gemm(const float* A, const float* Bmat, float* C,
                                              const float* bias, const float* resid,
                                              int M, int N, int K, int flags, float* outbase) {
  __shared__ float As[16][68];
  __shared__ float Bs[16][68];
  int m0 = blockIdx.x*64;
  int n0 = blockIdx.y*64;
  int tid = threadIdx.x;
  int tx = tid & 15, ty = tid >> 4;
  float acc[4][4] = {};
  for (int k0 = 0; k0 < K; k0 += 16) {
    {
      int kk = tid & 15, mb = tid >> 4;
      #pragma unroll
      for (int i = 0; i < 4; i++) {
        int m = mb + i*16;
        int gm = m0 + m; if (gm >= M) gm = M-1;
        As[kk][m] = A[(size_t)gm*K + k0 + kk];
      }
    }
    if (flags & GF_BT) {
      int kk = tid & 15, nb = tid >> 4;
      #pragma unroll
      for (int i = 0; i < 4; i++) {
        int n = nb + i*16;
        Bs[kk][n] = Bmat[(size_t)(n0 + n)*K + k0 + kk];
      }
    } else {
      int nn = tid & 63, kb = tid >> 6;
      #pragma unroll
      for (int i = 0; i < 4; i++) {
        int kk = kb + i*4;
        Bs[kk][nn] = Bmat[(size_t)(k0 + kk)*N + n0 + nn];
      }
    }
    __syncthreads();
    #pragma unroll
    for (int kk = 0; kk < 16; kk++) {
      float4 a  = *(const float4*)&As[kk][ty*4];
      float4 bv = *(const float4*)&Bs[kk][tx*4];
      float av[4] = {a.x, a.y, a.z, a.w};
      float bw[4] = {bv.x, bv.y, bv.z, bv.w};
      #pragma unroll
      for (int i = 0; i < 4; i++)
        #pragma unroll
        for (int j = 0; j < 4; j++)
          acc[i][j] += av[i]*bw[j];
    }
    __syncthreads();
  }
  #pragma unroll
  for (int i = 0; i < 4; i++) {
    int m = m0 + ty*4 + i;
    if (m >= M) continue;
    float* crow;
    if (flags & GF_SCAT) {
      int t = m >> 2, b = m & 3;
      crow = outbase + ((size_t)b*Sq + t)*Vc;
    } else {
      crow = C + (size_t)m*N;
    }
    #pragma unroll
    for (int j = 0; j < 4; j++) {
      int n = n0 + tx*4 + j;
      float v = acc[i][j];
      if (flags & GF_BIAS) v += bias[n];
      if (flags & GF_GELU) {
        float x = v;
        float uu = 0.7978845608028654f*(x + 0.044715f*x*x*x);
        float th = 1.f - 2.f/(expf(2.f*uu) + 1.f);   // tanh(uu)
        v = 0.5f*x*(1.f + th);
      }
      if (flags & GF_RES) v += resid[(size_t)m*N + n];
      crow[n] = v;
    }
  }
}

// per-(window, head) attention over the 65-token window
__global__ __launch_bounds__(256) void k_attn(const float* qkv, float* attno) {
  __shared__ float qs[Tw][68];
  __shared__ float ksh[Tw][68];
  __shared__ float ss[Tw][68];
  int wc = blockIdx.x >> 3;
  int h  = blockIdx.x & 7;
  int tid = threadIdx.x;
  size_t row0 = (size_t)wc*Tw;
  const float* qb = qkv + row0*(3*Dm) + h*64;
  for (int e = tid; e < Tw*64; e += 256) {
    int p = e >> 6, d = e & 63;
    qs[p][d]  = qb[(size_t)p*(3*Dm) + d];
    ksh[p][d] = qb[(size_t)p*(3*Dm) + Dm + d];
  }
  __syncthreads();
  for (int e = tid; e < Tw*Tw; e += 256) {
    int i = e / Tw, j = e % Tw;
    float v;
    if (j > i) v = -1e9f;
    else {
      float acc = 0.f;
      #pragma unroll 8
      for (int d = 0; d < 64; d++) acc += qs[i][d]*ksh[j][d];
      v = acc*0.125f;
    }
    ss[i][j] = v;
  }
  __syncthreads();
  if (tid < Tw) {
    int i = tid;
    float m = -1e30f;
    for (int j = 0; j < Tw; j++) m = fmaxf(m, ss[i][j]);
    float sum = 0.f;
    for (int j = 0; j < Tw; j++) { float eL = expf(ss[i][j] - m); ss[i][j] = eL; sum += eL; }
    float inv = 1.f/sum;
    for (int j = 0; j < Tw; j++) ss[i][j] *= inv;
  }
  __syncthreads();
  const float* vb = qkv + row0*(3*Dm) + 2*Dm + h*64;
  for (int e = tid; e < Tw*64; e += 256) {
    int i = e >> 6, d = e & 63;
    float acc = 0.f;
    for (int j = 0; j <= i; j++) acc += ss[i][j]*vb[(size_t)j*(3*Dm) + d];
    attno[(row0 + i)*Dm + h*64 + d] = acc;
  }
}

// ---------------- host launch ----------------
extern "C" void kernel_launch(void* const* d_in, const int* in_sizes, int n_in,
                              void* d_out, int out_size, void* d_ws, size_t ws_size,
                              hipStream_t stream) {
  const int*   ids    = (const int*)  d_in[0];
  const float* emb    = (const float*)d_in[1];
  const float* ln1g   = (const float*)d_in[2];
  const float* ln1b   = (const float*)d_in[3];
  const float* wqkv   = (const float*)d_in[4];
  const float* wo     = (const float*)d_in[5];
  const float* ln2g   = (const float*)d_in[6];
  const float* ln2b   = (const float*)d_in[7];
  const float* w1     = (const float*)d_in[8];
  const float* b1     = (const float*)d_in[9];
  const float* w2     = (const float*)d_in[10];
  const float* b2     = (const float*)d_in[11];
  const float* lnfg   = (const float*)d_in[12];
  const float* lnfb   = (const float*)d_in[13];
  const float* poolq  = (const float*)d_in[14];
  const float* poolwk = (const float*)d_in[15];
  const float* swin   = (const float*)d_in[16];
  const float* swdt   = (const float*)d_in[17];
  const float* sbdt   = (const float*)d_in[18];
  const float* sAlog  = (const float*)d_in[19];
  const float* swB    = (const float*)d_in[20];
  const float* swC    = (const float*)d_in[21];
  const float* sDd    = (const float*)d_in[22];
  const float* swout  = (const float*)d_in[23];
  float* out = (float*)d_out;
  float* ws  = (float*)d_ws;

  // workspace layout (float elements)
  size_t off = 0;
  auto alloc = [&](size_t n){ size_t o = off; off += n; return o; };
  size_t o_ssmvec = alloc((size_t)16*Bz*Dm);        // [16][B][D], slot 0 = zeros
  size_t o_h      = alloc((size_t)2*Bz*DIc*DSc);    // SSM hidden state (2 layers)
  size_t o_embseq = alloc((size_t)Bz*Sq*Dm);
  size_t o_u      = alloc((size_t)Dm);
  size_t o_P      = alloc((size_t)16*Bz*Dm);
  size_t o_Z      = alloc((size_t)16*Bz);
  size_t o_M      = alloc((size_t)16*Bz);
  size_t o_pool   = alloc((size_t)Bz*Dm);
  size_t o_xb     = alloc((size_t)Bz*Dm);
  size_t o_x1     = alloc((size_t)Bz*DIc);
  size_t o_zb     = alloc((size_t)Bz*DIc);
  size_t o_dt     = alloc((size_t)Bz*DIc);
  size_t o_Bm     = alloc((size_t)Bz*DSc);
  size_t o_Cm     = alloc((size_t)Bz*DSc);
  size_t o_y      = alloc((size_t)Bz*DIc);
  size_t o_yfin   = alloc((size_t)NWc*Dm);

  // chunk width: biggest that fits in ws (4608 floats per window-row)
  int CW = 128;
  while (CW > 16) {
    size_t need = off + (size_t)CW*Tw*(Dm + Dm + 3*Dm + DFFc);
    if (need*sizeof(float) <= ws_size) break;
    CW >>= 1;
  }
  int RC = CW*Tw;
  size_t o_xc  = off;
  size_t o_hin = o_xc  + (size_t)RC*Dm;
  size_t o_qkv = o_hin + (size_t)RC*Dm;
  size_t o_ffh = o_qkv + (size_t)RC*3*Dm;
  int NCH = NWc/CW;

  // ---- phase 0: parallel precompute ----
  int nz = 16*Bz*Dm + 2*Bz*DIc*DSc;                // ssm_vec + h are adjacent
  k_zero<<<(nz + 255)/256, 256, 0, stream>>>(ws + o_ssmvec, nz);
  k_gather<<<(Bz*Sq*Dm)/256, 256, 0, stream>>>(ids, emb, ws + o_embseq);
  k_uvec<<<2, 256, 0, stream>>>(poolwk, poolq, ws + o_u);
  k_poolpre<<<15*Bz, 256, 0, stream>>>(ws + o_embseq, ws + o_u,
                                       ws + o_P, ws + o_Z, ws + o_M);

  // ---- phase 1: 15 sequential SSM write steps ----
  for (int kk = 1; kk <= 15; kk++) {
    for (int l = 0; l < 2; l++) {
      k_ssm_xz<<<dim3(32, Bz), 256, 0, stream>>>(
          swin + (size_t)l*Dm*2*DIc, ws + o_ssmvec, ws + o_P, ws + o_Z, ws + o_M,
          ws + o_u, ws + o_xb, ws + o_pool, ws + o_x1, ws + o_zb, kk, l);
      k_ssm_proj<<<dim3(17, Bz), 256, 0, stream>>>(
          swdt + (size_t)l*DIc*DIc, sbdt + (size_t)l*DIc,
          swB + (size_t)l*DIc*DSc, swC + (size_t)l*DIc*DSc,
          ws + o_x1, ws + o_dt, ws + o_Bm, ws + o_Cm);
      k_ssm_hy<<<16, 256, 0, stream>>>(
          sAlog + (size_t)l*DIc*DSc, sDd + (size_t)l*DIc,
          ws + o_dt, ws + o_x1, ws + o_zb, ws + o_Bm, ws + o_Cm,
          ws + o_h + (size_t)l*Bz*DIc*DSc, ws + o_y);
      k_ssm_out<<<dim3(8, Bz), 256, 0, stream>>>(
          swout + (size_t)l*DIc*Dm, ws + o_y,
          (l == 0 ? ws + o_pool : ws + o_xb),
          (l == 0 ? ws + o_xb   : ws + o_ssmvec + (size_t)kk*Bz*Dm));
    }
  }

  // ---- phase 2: batched transformer over all 1024 windows, chunked ----
  int mt = (RC + 63)/64;
  for (int c = 0; c < NCH; c++) {
    k_build<<<RC*2, 256, 0, stream>>>(ws + o_embseq, ws + o_ssmvec, ws + o_xc, c, CW);
    for (int l = 0; l < 2; l++) {
      k_ln<<<RC, 256, 0, stream>>>(ws + o_xc, ws + o_hin, ln1g + l*Dm, ln1b + l*Dm);
      k_gemm<<<dim3(mt, 24), 256, 0, stream>>>(
          ws + o_hin, wqkv + (size_t)l*Dm*3*Dm, ws + o_qkv,
          nullptr, nullptr, RC, 3*Dm, Dm, 0, nullptr);
      k_attn<<<CW*NHd, 256, 0, stream>>>(ws + o_qkv, ws + o_hin);
      k_gemm<<<dim3(mt, 8), 256, 0, stream>>>(
          ws + o_hin, wo + (size_t)l*Dm*Dm, ws + o_xc,
          nullptr, ws + o_xc, RC, Dm, Dm, GF_RES, nullptr);
      k_ln<<<RC, 256, 0, stream>>>(ws + o_xc, ws + o_qkv, ln2g + l*Dm, ln2b + l*Dm);
      k_gemm<<<dim3(mt, 32), 256, 0, stream>>>(
          ws + o_qkv, w1 + (size_t)l*Dm*DFFc, ws + o_ffh,
          b1 + (size_t)l*DFFc, nullptr, RC, DFFc, Dm, GF_BIAS|GF_GELU, nullptr);
      k_gemm<<<dim3(mt, 8), 256, 0, stream>>>(
          ws + o_ffh, w2 + (size_t)l*DFFc*Dm, ws + o_xc,
          b2 + (size_t)l*Dm, ws + o_xc, RC, Dm, DFFc, GF_BIAS|GF_RES, nullptr);
    }
    k_lnlast<<<CW, 256, 0, stream>>>(ws + o_xc, ws + o_yfin, lnfg, lnfb, c, CW);
  }

  // ---- lm_head: logits = yfinal @ embedding^T, scattered to (B,S,V) ----
  k_gemm<<<dim3(NWc/64, Vc/64), 256, 0, stream>>>(
      ws + o_yfin, emb, nullptr, nullptr, nullptr,
      NWc, Vc, Dm, GF_BT|GF_SCAT, out);
}

// Round 2
// 6579.259 us; speedup vs baseline: 2.6244x; 2.6244x over previous
//
#include <hip/hip_runtime.h>
#include <hip/hip_bf16.h>

// ---------------- architecture constants ----------------
namespace {
constexpr int Bz  = 4;      // batch
constexpr int Sq  = 256;    // seq len
constexpr int Dm  = 512;    // d_model
constexpr int NHd = 8;      // heads
constexpr int Tw  = 65;     // window (1 ssm + 64 input)
constexpr int DFFc= 2048;   // ffn hidden
constexpr int Vc  = 32000;  // vocab
constexpr int DKc = 64;     // pool key dim
constexpr int DIc = 1024;   // ssm d_inner
constexpr int DSc = 16;     // ssm d_state
constexpr int NWc = Bz*Sq;  // 1024 windows

constexpr int GF_BIAS = 1;
constexpr int GF_GELU = 2;
constexpr int GF_RES  = 4;
constexpr int GF_SCAT = 8;
constexpr int GF_OBF  = 16;   // bf16 output
}

typedef __hip_bfloat16 bf16;

__device__ __forceinline__ void async16(const void* g, void* l) {
  __builtin_amdgcn_global_load_lds(
      (const __attribute__((address_space(1))) unsigned int*)g,
      (__attribute__((address_space(3))) unsigned int*)l, 16, 0, 0);
}
__device__ __forceinline__ int imin(int a, int b) { return a < b ? a : b; }

// ---------------- utility kernels ----------------
__global__ __launch_bounds__(256) void k_zero(float* p, int n) {
  int i = blockIdx.x*256 + threadIdx.x;
  if (i < n) p[i] = 0.f;
}

__global__ __launch_bounds__(256) void k_gather(const int* ids, const float* emb, float* emb_seq) {
  int e = blockIdx.x*256 + threadIdx.x;          // Bz*Sq*Dm total
  int d  = e & (Dm-1);
  int bs = e >> 9;                               // b*Sq + s
  emb_seq[e] = emb[(size_t)ids[bs]*Dm + d];
}

// straight fp32 -> bf16 convert
__global__ __launch_bounds__(256) void k_cvt(const float* in, bf16* out, int n) {
  int i = blockIdx.x*256 + threadIdx.x;
  if (i < n) out[i] = (bf16)in[i];
}

// transpose+convert: out[n*K+k] = bf16(in[k*N+n]); K,N multiples of 32
__global__ __launch_bounds__(256) void k_wconv_t(const float* in, bf16* out, int K, int N) {
  __shared__ float t[32][33];
  int k0 = blockIdx.x*32, n0 = blockIdx.y*32;
  int tx = threadIdx.x & 31, ty = threadIdx.x >> 5;  // 32 x 8
  #pragma unroll
  for (int i = 0; i < 4; i++)
    t[ty + i*8][tx] = in[(size_t)(k0 + ty + i*8)*N + n0 + tx];
  __syncthreads();
  #pragma unroll
  for (int i = 0; i < 4; i++)
    out[(size_t)(n0 + ty + i*8)*K + k0 + tx] = (bf16)t[tx][ty + i*8];
}

__global__ __launch_bounds__(256) void k_uvec(const float* pool_wk, const float* pool_q, float* u) {
  int d = blockIdx.x*256 + threadIdx.x;
  if (d < Dm) {
    float acc = 0.f;
    for (int e = 0; e < DKc; e++) acc += pool_wk[d*DKc + e]*pool_q[e];
    u[d] = acc;
  }
}

// Precompute pool softmax partials over the 64 input slots for each write step.
__global__ __launch_bounds__(256) void k_poolpre(const float* emb_seq, const float* u,
                                                 float* Pres, float* Zres, float* Mres) {
  int kk = blockIdx.x / Bz + 1;   // 1..15
  int b  = blockIdx.x % Bz;
  int t  = kk*16;
  __shared__ float sj[64];
  __shared__ float ej[64];
  __shared__ float sM;
  int tid = threadIdx.x;
  if (tid < 64) {
    int j = tid + 1;              // window pos 1..64
    int idx = t - 64 + j;
    float s = 0.f;
    if (idx >= 0) {
      const float* row = emb_seq + ((size_t)b*Sq + idx)*Dm;
      float acc = 0.f;
      for (int d = 0; d < Dm; d++) acc += row[d]*u[d];
      s = acc*0.125f;
    }
    sj[tid] = s;
  }
  __syncthreads();
  if (tid == 0) {
    float m = -1e30f;
    for (int j = 0; j < 64; j++) m = fmaxf(m, sj[j]);
    sM = m;
  }
  __syncthreads();
  if (tid < 64) ej[tid] = expf(sj[tid] - sM);
  __syncthreads();
  if (tid == 0) {
    float z = 0.f;
    for (int j = 0; j < 64; j++) z += ej[j];
    Zres[kk*Bz + b] = z;
    Mres[kk*Bz + b] = sM;
  }
  __syncthreads();
  for (int d = tid; d < Dm; d += 256) {
    float acc = 0.f;
    for (int j = 1; j <= 64; j++) {
      int idx = t - 64 + j;
      if (idx >= 0) acc += ej[j-1]*emb_seq[((size_t)b*Sq + idx)*Dm + d];
    }
    Pres[((size_t)kk*Bz + b)*Dm + d] = acc;
  }
}

// ---------------- phase 1: sequential SSM (write steps only) ----------------
__global__ __launch_bounds__(256) void k_ssm_xz(const float* win, const float* ssm_vec,
                                                const float* Pres, const float* Zres, const float* Mres,
                                                const float* u, const float* xb, float* pooled,
                                                float* x1buf, float* zbuf, int kk, int layer) {
  int jg = blockIdx.x;       // 0..31
  int b  = blockIdx.y;
  int tid = threadIdx.x;
  __shared__ float xin[Dm];
  __shared__ float red[256];
  __shared__ float r2[4][64];
  if (layer == 0) {
    const float* sv = ssm_vec + ((size_t)(kk-1)*Bz + b)*Dm;
    float p = 0.f;
    for (int i = tid; i < Dm; i += 256) p += sv[i]*u[i];
    red[tid] = p; __syncthreads();
    for (int s = 128; s > 0; s >>= 1) { if (tid < s) red[tid] += red[tid+s]; __syncthreads(); }
    float s0  = red[0]*0.125f;
    float e0  = expf(s0 - Mres[kk*Bz + b]);
    float inv = 1.f/(e0 + Zres[kk*Bz + b]);
    const float* Pr = Pres + ((size_t)kk*Bz + b)*Dm;
    for (int i = tid; i < Dm; i += 256) {
      float val = (e0*sv[i] + Pr[i])*inv;
      xin[i] = val;
      if (jg == 0) pooled[b*Dm + i] = val;
    }
  } else {
    for (int i = tid; i < Dm; i += 256) xin[i] = xb[b*Dm + i];
  }
  __syncthreads();
  int ks = tid >> 6, jl = tid & 63;
  int j  = jg*64 + jl;                  // 0..2047
  const float* w = win + j;
  float acc = 0.f;
  int k0 = ks*128;
  #pragma unroll 8
  for (int k = k0; k < k0 + 128; k++) acc += xin[k]*w[(size_t)k*(2*DIc)];
  r2[ks][jl] = acc; __syncthreads();
  if (tid < 64) {
    int jj = jg*64 + tid;
    float v = r2[0][tid] + r2[1][tid] + r2[2][tid] + r2[3][tid];
    if (jj < DIc) x1buf[b*DIc + jj] = v;
    else          zbuf[b*DIc + (jj - DIc)] = v;
  }
}

__global__ __launch_bounds__(256) void k_ssm_proj(const float* wdt, const float* bdt,
                                                  const float* wB, const float* wC,
                                                  const float* x1buf, float* dtbuf,
                                                  float* Bmbuf, float* Cmbuf) {
  int bx = blockIdx.x;       // 0..16
  int b  = blockIdx.y;
  int tid = threadIdx.x;
  __shared__ float x1[DIc];
  __shared__ float r2[4][64];
  __shared__ float r3[8][32];
  for (int i = tid; i < DIc; i += 256) x1[i] = x1buf[b*DIc + i];
  __syncthreads();
  if (bx < 16) {
    int ks = tid >> 6, jl = tid & 63;
    int j = bx*64 + jl;
    const float* w = wdt + j;
    float acc = 0.f;
    int k0 = ks*256;
    #pragma unroll 8
    for (int k = k0; k < k0 + 256; k++) acc += x1[k]*w[(size_t)k*DIc];
    r2[ks][jl] = acc; __syncthreads();
    if (tid < 64) {
      int jj = bx*64 + tid;
      float v = r2[0][tid] + r2[1][tid] + r2[2][tid] + r2[3][tid] + bdt[jj];
      dtbuf[b*DIc + jj] = fmaxf(v, 0.f) + log1pf(expf(-fabsf(v)));   // stable softplus
    }
  } else {
    int ks = tid >> 5, jl = tid & 31;
    int s  = jl & 15;
    const float* w = (jl < 16 ? wB : wC) + s;
    float acc = 0.f;
    int k0 = ks*128;
    #pragma unroll 8
    for (int k = k0; k < k0 + 128; k++) acc += x1[k]*w[(size_t)k*DSc];
    r3[ks][jl] = acc; __syncthreads();
    if (tid < 32) {
      float v = 0.f;
      for (int q = 0; q < 8; q++) v += r3[q][tid];
      if (tid < 16) Bmbuf[b*DSc + tid] = v;
      else          Cmbuf[b*DSc + (tid - 16)] = v;
    }
  }
}

__global__ __launch_bounds__(256) void k_ssm_hy(const float* Alog, const float* ssmD,
                                                const float* dtbuf, const float* x1buf,
                                                const float* zbuf, const float* Bmbuf,
                                                const float* Cmbuf, float* hstate, float* ybuf) {
  int g = blockIdx.x*256 + threadIdx.x;   // 0..4095
  int b = g >> 10;
  int d = g & 1023;
  float dt = dtbuf[g];
  float x1 = x1buf[g];
  float z  = zbuf[g];
  float sil = z / (1.f + expf(-z));
  float* h = hstate + ((size_t)b*DIc + d)*DSc;
  const float* Ar = Alog + (size_t)d*DSc;
  float acc = 0.f;
  #pragma unroll
  for (int s = 0; s < DSc; s++) {
    float A  = -expf(Ar[s]);
    float hn = expf(dt*A)*h[s] + dt*Bmbuf[b*DSc + s]*x1;
    h[s] = hn;
    acc += hn*Cmbuf[b*DSc + s];
  }
  ybuf[g] = (acc + ssmD[d]*x1)*sil;
}

__global__ __launch_bounds__(256) void k_ssm_out(const float* wout, const float* ybuf,
                                                 const float* xbase, float* dst) {
  int jg = blockIdx.x;       // 0..7
  int b  = blockIdx.y;
  int tid = threadIdx.x;
  __shared__ float y[DIc];
  __shared__ float r2[4][64];
  for (int i = tid; i < DIc; i += 256) y[i] = ybuf[b*DIc + i];
  __syncthreads();
  int ks = tid >> 6, jl = tid & 63;
  int j = jg*64 + jl;
  const float* w = wout + j;
  float acc = 0.f;
  int k0 = ks*256;
  #pragma unroll 8
  for (int k = k0; k < k0 + 256; k++) acc += y[k]*w[(size_t)k*Dm];
  r2[ks][jl] = acc; __syncthreads();
  if (tid < 64) {
    int jj = jg*64 + tid;
    dst[b*Dm + jj] = xbase[b*Dm + jj] + r2[0][tid] + r2[1][tid] + r2[2][tid] + r2[3][tid];
  }
}

// ---------------- phase 2: parallel transformer over all windows ----------------
__global__ __launch_bounds__(256) void k_build(const float* emb_seq, const float* ssm_vec,
                                               float* xc, int c, int CW) {
  int e = blockIdx.x*256 + threadIdx.x;   // RC*Dm total
  int d = e & (Dm-1);
  int r = e >> 9;
  int wc = r / Tw, p = r % Tw;
  int w  = c*CW + wc;
  int t  = w >> 2, b = w & 3;
  float val;
  if (p == 0) {
    int kused = (t == 0) ? 0 : ((t-1) >> 4);
    val = ssm_vec[((size_t)kused*Bz + b)*Dm + d];
  } else {
    int idx = t - 64 + p;
    val = (idx >= 0) ? emb_seq[((size_t)b*Sq + idx)*Dm + d] : 0.f;
  }
  xc[e] = val;
}

// LN: fp32 in -> bf16 out
__global__ __launch_bounds__(256) void k_ln(const float* src, bf16* dst,
                                            const float* g, const float* bb) {
  int r = blockIdx.x;
  int tid = threadIdx.x;
  const float* x = src + (size_t)r*Dm;
  float v0 = x[tid], v1 = x[tid + 256];
  __shared__ float rs[256], rq[256];
  rs[tid] = v0 + v1; rq[tid] = v0*v0 + v1*v1;
  __syncthreads();
  for (int s = 128; s > 0; s >>= 1) {
    if (tid < s) { rs[tid] += rs[tid+s]; rq[tid] += rq[tid+s]; }
    __syncthreads();
  }
  float mu   = rs[0]*(1.f/Dm);
  float var  = rq[0]*(1.f/Dm) - mu*mu;
  float rstd = rsqrtf(var + 1e-5f);
  bf16* y = dst + (size_t)r*Dm;
  y[tid]       = (bf16)((v0 - mu)*rstd*g[tid]       + bb[tid]);
  y[tid + 256] = (bf16)((v1 - mu)*rstd*g[tid + 256] + bb[tid + 256]);
}

// final LN over last window position only -> yfinal[w] (bf16)
__global__ __launch_bounds__(256) void k_lnlast(const float* xc, bf16* yfinal,
                                                const float* g, const float* bb, int c, int CW) {
  int wc = blockIdx.x;
  int r  = wc*Tw + (Tw-1);
  int w  = c*CW + wc;
  int tid = threadIdx.x;
  const float* x = xc + (size_t)r*Dm;
  float v0 = x[tid], v1 = x[tid + 256];
  __shared__ float rs[256], rq[256];
  rs[tid] = v0 + v1; rq[tid] = v0*v0 + v1*v1;
  __syncthreads();
  for (int s = 128; s > 0; s >>= 1) {
    if (tid < s) { rs[tid] += rs[tid+s]; rq[tid] += rq[tid+s]; }
    __syncthreads();
  }
  float mu   = rs[0]*(1.f/Dm);
  float var  = rq[0]*(1.f/Dm) - mu*mu;
  float rstd = rsqrtf(var + 1e-5f);
  bf16* y = yfinal + (size_t)w*Dm;
  y[tid]       = (bf16)((v0 - mu)*rstd*g[tid]       + bb[tid]);
  y[tid + 256] = (bf16)((v1 - mu)*rstd*g[tid + 256] + bb[tid + 256]);
}

// ---------------- bf16 MFMA GEMM (m97 recipe) ----------------
// C[M,N] = A[M,K] @ Bt[N,K]^T; A,Bt bf16 row-major; TM=128, BK=32, TN in {128,64}.
// 256 threads = 4 waves as 2x2; global_load_lds width-16 staging; unpadded LDS.
template<int TN>
__global__ __launch_bounds__(256) void k_mgemm(
    const bf16* __restrict__ A, const bf16* __restrict__ Bt, void* __restrict__ C,
    const float* __restrict__ bias, const float* __restrict__ resid,
    int M, int N, int K, int flags, float* __restrict__ outbase) {
  constexpr int TM = 128, BK = 32;
  constexpr int WN = TN/2, NF = WN/16;
  __shared__ bf16 As[TM*BK];
  __shared__ bf16 Bs[TN*BK];
  const int tid  = threadIdx.x;
  const int wave = tid >> 6, lane = tid & 63;
  const int m0 = blockIdx.x*TM, n0 = blockIdx.y*TN;
  const int wm = (wave>>1)*64, wn = (wave&1)*WN;
  using frag = __attribute__((ext_vector_type(8))) short;
  using f4   = __attribute__((ext_vector_type(4))) float;
  f4 acc[4][NF];
  #pragma unroll
  for (int i = 0; i < 4; i++)
    #pragma unroll
    for (int j = 0; j < NF; j++) acc[i][j] = (f4){0.f, 0.f, 0.f, 0.f};

  // staging address setup: lane covers (row = chunkrow + lane/4, col = (lane%4)*8)
  const int srow = lane >> 2;
  const int scol = (lane & 3)*8;
  const int am0 = imin(m0 + wave*32 + srow,      M-1);
  const int am1 = imin(m0 + wave*32 + 16 + srow, M-1);
  const bf16* gA0 = A + (size_t)am0*K + scol;
  const bf16* gA1 = A + (size_t)am1*K + scol;
  bf16* lA0 = As + wave*1024;
  bf16* lA1 = As + wave*1024 + 512;
  const bf16 *gB0, *gB1 = nullptr;
  bf16 *lB0, *lB1 = nullptr;
  if (TN == 128) {
    gB0 = Bt + (size_t)imin(n0 + wave*32 + srow,      N-1)*K + scol;
    gB1 = Bt + (size_t)imin(n0 + wave*32 + 16 + srow, N-1)*K + scol;
    lB0 = Bs + wave*1024;
    lB1 = Bs + wave*1024 + 512;
  } else {
    gB0 = Bt + (size_t)imin(n0 + wave*16 + srow, N-1)*K + scol;
    lB0 = Bs + wave*512;
  }

  const int fr = lane & 15;
  const int q8 = (lane >> 4)*8;
  for (int k0 = 0; k0 < K; k0 += BK) {
    async16(gA0 + k0, lA0);
    async16(gA1 + k0, lA1);
    async16(gB0 + k0, lB0);
    if (TN == 128) async16(gB1 + k0, lB1);
    __syncthreads();
    frag af[4], bfr[NF];
    #pragma unroll
    for (int i = 0; i < 4; i++)
      af[i] = *(const frag*)(As + (wm + i*16 + fr)*BK + q8);
    #pragma unroll
    for (int j = 0; j < NF; j++)
      bfr[j] = *(const frag*)(Bs + (wn + j*16 + fr)*BK + q8);
    #pragma unroll
    for (int i = 0; i < 4; i++)
      #pragma unroll
      for (int j = 0; j < NF; j++)
        acc[i][j] = __builtin_amdgcn_mfma_f32_16x16x32_bf16(af[i], bfr[j], acc[i][j], 0, 0, 0);
    __syncthreads();
  }

  // epilogue: C/D map col=lane&15, row=(lane>>4)*4+reg  [measured m89/m91]
  const int col = lane & 15, r0 = (lane >> 4)*4;
  #pragma unroll
  for (int i = 0; i < 4; i++) {
    #pragma unroll
    for (int j = 0; j < NF; j++) {
      #pragma unroll
      for (int r = 0; r < 4; r++) {
        int gm = m0 + wm + i*16 + r0 + r;
        int gn = n0 + wn + j*16 + col;
        if (gm >= M) continue;
        float v = acc[i][j][r];
        if (flags & GF_BIAS) v += bias[gn];
        if (flags & GF_GELU) {
          float x  = v;
          float uu = 0.7978845608028654f*(x + 0.044715f*x*x*x);
          float th = 1.f - 2.f/(expf(2.f*uu) + 1.f);
          v = 0.5f*x*(1.f + th);
        }
        if (flags & GF_RES) v += resid[(size_t)gm*N + gn];
        if (flags & GF_SCAT) {
          int t = gm >> 2, b = gm & 3;
          outbase[((size_t)b*Sq + t)*Vc + gn] = v;
        } else if (flags & GF_OBF) {
          ((bf16*)C)[(size_t)gm*N + gn] = (bf16)v;
        } else {
          ((float*)C)[(size_t)gm*N + gn] = v;
        }
      }
    }
  }
}

// per-(window, head) attention over the 65-token window; bf16 qkv in, bf16 out
__global__ __launch_bounds__(256) void k_attn(const bf16* qkv, bf16* attno) {
  __shared__ float qs[Tw][68];   // q, then reused for v
  __shared__ float ksh[Tw][68];
  __shared__ float ss[Tw][68];
  int wc = blockIdx.x >> 3;
  int h  = blockIdx.x & 7;
  int tid = threadIdx.x;
  size_t row0 = (size_t)wc*Tw;
  const bf16* qb = qkv + row0*(3*Dm) + h*64;
  for (int e = tid; e < Tw*64; e += 256) {
    int p = e >> 6, d = e & 63;
    qs[p][d]  = __bfloat162float(qb[(size_t)p*(3*Dm) + d]);
    ksh[p][d] = __bfloat162float(qb[(size_t)p*(3*Dm) + Dm + d]);
  }
  __syncthreads();
  for (int e = tid; e < Tw*Tw; e += 256) {
    int i = e / Tw, j = e % Tw;
    float v;
    if (j > i) v = -1e9f;
    else {
      float acc = 0.f;
      #pragma unroll 8
      for (int d = 0; d < 64; d++) acc += qs[i][d]*ksh[j][d];
      v = acc*0.125f;
    }
    ss[i][j] = v;
  }
  __syncthreads();
  if (tid < Tw) {
    int i = tid;
    float m = -1e30f;
    for (int j = 0; j < Tw; j++) m = fmaxf(m, ss[i][j]);
    float sum = 0.f;
    for (int j = 0; j < Tw; j++) { float eL = expf(ss[i][j] - m); ss[i][j] = eL; sum += eL; }
    float inv = 1.f/sum;
    for (int j = 0; j < Tw; j++) ss[i][j] *= inv;
  }
  __syncthreads();
  // stage V into qs (q no longer needed)
  const bf16* vb = qkv + row0*(3*Dm) + 2*Dm + h*64;
  for (int e = tid; e < Tw*64; e += 256) {
    int p = e >> 6, d = e & 63;
    qs[p][d] = __bfloat162float(vb[(size_t)p*(3*Dm) + d]);
  }
  __syncthreads();
  for (int e = tid; e < Tw*64; e += 256) {
    int i = e >> 6, d = e & 63;
    float acc = 0.f;
    for (int j = 0; j <= i; j++) acc += ss[i][j]*qs[j][d];
    attno[(row0 + i)*Dm + h*64 + d] = (bf16)acc;
  }
}

// ---------------- host launch ----------------
extern "C" void kernel_launch(void* const* d_in, const int* in_sizes, int n_in,
                              void* d_out, int out_size, void* d_ws, size_t ws_size,
                              hipStream_t stream) {
  const int*   ids    = (const int*)  d_in[0];
  const float* emb    = (const float*)d_in[1];
  const float* ln1g   = (const float*)d_in[2];
  const float* ln1b   = (const float*)d_in[3];
  const float* wqkv   = (const float*)d_in[4];
  const float* wo     = (const float*)d_in[5];
  const float* ln2g   = (const float*)d_in[6];
  const float* ln2b   = (const float*)d_in[7];
  const float* w1     = (const float*)d_in[8];
  const float* b1     = (const float*)d_in[9];
  const float* w2     = (const float*)d_in[10];
  const float* b2     = (const float*)d_in[11];
  const float* lnfg   = (const float*)d_in[12];
  const float* lnfb   = (const float*)d_in[13];
  const float* poolq  = (const float*)d_in[14];
  const float* poolwk = (const float*)d_in[15];
  const float* swin   = (const float*)d_in[16];
  const float* swdt   = (const float*)d_in[17];
  const float* sbdt   = (const float*)d_in[18];
  const float* sAlog  = (const float*)d_in[19];
  const float* swB    = (const float*)d_in[20];
  const float* swC    = (const float*)d_in[21];
  const float* sDd    = (const float*)d_in[22];
  const float* swout  = (const float*)d_in[23];
  float* out = (float*)d_out;
  char*  wsb = (char*)d_ws;

  // byte allocator, 256B aligned
  size_t off = 0;
  auto alloc = [&](size_t bytes) {
    size_t o = off;
    off += (bytes + 255) & ~(size_t)255;
    return o;
  };
  size_t o_ssmvec = alloc((size_t)16*Bz*Dm*4);          // fp32, slot 0 = zeros
  size_t o_h      = alloc((size_t)2*Bz*DIc*DSc*4);      // fp32 (adjacent to ssmvec: both 256-mult)
  size_t o_embseq = alloc((size_t)Bz*Sq*Dm*4);
  size_t o_u      = alloc((size_t)Dm*4);
  size_t o_P      = alloc((size_t)16*Bz*Dm*4);
  size_t o_Z      = alloc((size_t)16*Bz*4);
  size_t o_M      = alloc((size_t)16*Bz*4);
  size_t o_pool   = alloc((size_t)Bz*Dm*4);
  size_t o_xb     = alloc((size_t)Bz*Dm*4);
  size_t o_x1     = alloc((size_t)Bz*DIc*4);
  size_t o_zb     = alloc((size_t)Bz*DIc*4);
  size_t o_dt     = alloc((size_t)Bz*DIc*4);
  size_t o_Bm     = alloc((size_t)Bz*DSc*4);
  size_t o_Cm     = alloc((size_t)Bz*DSc*4);
  size_t o_y      = alloc((size_t)Bz*DIc*4);
  size_t o_yfin   = alloc((size_t)NWc*Dm*2);            // bf16
  // bf16 weights (transposed to [N][K])
  size_t o_wqkvT  = alloc((size_t)2*3*Dm*Dm*2);
  size_t o_woT    = alloc((size_t)2*Dm*Dm*2);
  size_t o_w1T    = alloc((size_t)2*DFFc*Dm*2);
  size_t o_w2T    = alloc((size_t)2*Dm*DFFc*2);
  size_t o_embbf  = alloc((size_t)Vc*Dm*2);

  // chunk width (bytes/window-row: xc 2048 + hbf 1024 + qkv 3072 + ffh 4096)
  int CW = 128;
  while (CW > 16) {
    size_t need = off + (size_t)CW*Tw*(Dm*4 + Dm*2 + 3*Dm*2 + DFFc*2) + 4096;
    if (need <= ws_size) break;
    CW >>= 1;
  }
  int RC = CW*Tw;
  size_t o_xc  = alloc((size_t)RC*Dm*4);                // fp32 residual stream
  size_t o_hbf = alloc((size_t)RC*Dm*2);                // bf16 LN/attn out
  size_t o_qkv = alloc((size_t)RC*3*Dm*2);              // bf16
  size_t o_ffh = alloc((size_t)RC*DFFc*2);              // bf16
  int NCH = NWc/CW;

  float* f_ssmvec = (float*)(wsb + o_ssmvec);
  float* f_embseq = (float*)(wsb + o_embseq);
  bf16*  b_yfin   = (bf16*) (wsb + o_yfin);
  bf16*  b_wqkvT  = (bf16*) (wsb + o_wqkvT);
  bf16*  b_woT    = (bf16*) (wsb + o_woT);
  bf16*  b_w1T    = (bf16*) (wsb + o_w1T);
  bf16*  b_w2T    = (bf16*) (wsb + o_w2T);
  bf16*  b_embbf  = (bf16*) (wsb + o_embbf);
  float* f_xc     = (float*)(wsb + o_xc);
  bf16*  b_hbf    = (bf16*) (wsb + o_hbf);
  bf16*  b_qkv    = (bf16*) (wsb + o_qkv);
  bf16*  b_ffh    = (bf16*) (wsb + o_ffh);

  // ---- phase 0: zero state, gather, weight conversion ----
  int nz = (16*Bz*Dm) + (2*Bz*DIc*DSc);                 // ssmvec + h (contiguous)
  k_zero<<<(nz + 255)/256, 256, 0, stream>>>(f_ssmvec, nz);
  k_gather<<<(Bz*Sq*Dm)/256, 256, 0, stream>>>(ids, emb, f_embseq);
  k_uvec<<<2, 256, 0, stream>>>(poolwk, poolq, (float*)(wsb + o_u));
  k_poolpre<<<15*Bz, 256, 0, stream>>>(f_embseq, (float*)(wsb + o_u),
                                       (float*)(wsb + o_P), (float*)(wsb + o_Z),
                                       (float*)(wsb + o_M));
  for (int l = 0; l < 2; l++) {
    k_wconv_t<<<dim3(Dm/32, 3*Dm/32), 256, 0, stream>>>(
        wqkv + (size_t)l*Dm*3*Dm, b_wqkvT + (size_t)l*3*Dm*Dm, Dm, 3*Dm);
    k_wconv_t<<<dim3(Dm/32, Dm/32), 256, 0, stream>>>(
        wo + (size_t)l*Dm*Dm, b_woT + (size_t)l*Dm*Dm, Dm, Dm);
    k_wconv_t<<<dim3(Dm/32, DFFc/32), 256, 0, stream>>>(
        w1 + (size_t)l*Dm*DFFc, b_w1T + (size_t)l*DFFc*Dm, Dm, DFFc);
    k_wconv_t<<<dim3(DFFc/32, Dm/32), 256, 0, stream>>>(
        w2 + (size_t)l*DFFc*Dm, b_w2T + (size_t)l*Dm*DFFc, DFFc, Dm);
  }
  k_cvt<<<(Vc*Dm)/256, 256, 0, stream>>>(emb, b_embbf, Vc*Dm);

  // ---- phase 1: 15 sequential SSM write steps ----
  for (int kk = 1; kk <= 15; kk++) {
    for (int l = 0; l < 2; l++) {
      k_ssm_xz<<<dim3(32, Bz), 256, 0, stream>>>(
          swin + (size_t)l*Dm*2*DIc, f_ssmvec,
          (float*)(wsb + o_P), (float*)(wsb + o_Z), (float*)(wsb + o_M),
          (float*)(wsb + o_u), (float*)(wsb + o_xb), (float*)(wsb + o_pool),
          (float*)(wsb + o_x1), (float*)(wsb + o_zb), kk, l);
      k_ssm_proj<<<dim3(17, Bz), 256, 0, stream>>>(
          swdt + (size_t)l*DIc*DIc, sbdt + (size_t)l*DIc,
          swB + (size_t)l*DIc*DSc, swC + (size_t)l*DIc*DSc,
          (float*)(wsb + o_x1), (float*)(wsb + o_dt),
          (float*)(wsb + o_Bm), (float*)(wsb + o_Cm));
      k_ssm_hy<<<16, 256, 0, stream>>>(
          sAlog + (size_t)l*DIc*DSc, sDd + (size_t)l*DIc,
          (float*)(wsb + o_dt), (float*)(wsb + o_x1), (float*)(wsb + o_zb),
          (float*)(wsb + o_Bm), (float*)(wsb + o_Cm),
          (float*)(wsb + o_h) + (size_t)l*Bz*DIc*DSc, (float*)(wsb + o_y));
      k_ssm_out<<<dim3(8, Bz), 256, 0, stream>>>(
          swout + (size_t)l*DIc*Dm, (float*)(wsb + o_y),
          (l == 0 ? (float*)(wsb + o_pool) : (float*)(wsb + o_xb)),
          (l == 0 ? (float*)(wsb + o_xb)   : f_ssmvec + (size_t)kk*Bz*Dm));
    }
  }

  // ---- phase 2: batched transformer over all 1024 windows, chunked ----
  int mt = (RC + 127)/128;
  for (int c = 0; c < NCH; c++) {
    k_build<<<RC*2, 256, 0, stream>>>(f_embseq, f_ssmvec, f_xc, c, CW);
    for (int l = 0; l < 2; l++) {
      k_ln<<<RC, 256, 0, stream>>>(f_xc, b_hbf, ln1g + l*Dm, ln1b + l*Dm);
      k_mgemm<128><<<dim3(mt, 3*Dm/128), 256, 0, stream>>>(
          b_hbf, b_wqkvT + (size_t)l*3*Dm*Dm, b_qkv,
          nullptr, nullptr, RC, 3*Dm, Dm, GF_OBF, nullptr);
      k_attn<<<CW*NHd, 256, 0, stream>>>(b_qkv, b_hbf);
      k_mgemm<64><<<dim3(mt, Dm/64), 256, 0, stream>>>(
          b_hbf, b_woT + (size_t)l*Dm*Dm, f_xc,
          nullptr, f_xc, RC, Dm, Dm, GF_RES, nullptr);
      k_ln<<<RC, 256, 0, stream>>>(f_xc, b_hbf, ln2g + l*Dm, ln2b + l*Dm);
      k_mgemm<128><<<dim3(mt, DFFc/128), 256, 0, stream>>>(
          b_hbf, b_w1T + (size_t)l*DFFc*Dm, b_ffh,
          b1 + (size_t)l*DFFc, nullptr, RC, DFFc, Dm, GF_BIAS|GF_GELU|GF_OBF, nullptr);
      k_mgemm<64><<<dim3(mt, Dm/64), 256, 0, stream>>>(
          b_ffh, b_w2T + (size_t)l*Dm*DFFc, f_xc,
          b2 + (size_t)l*Dm, f_xc, RC, Dm, DFFc, GF_BIAS|GF_RES, nullptr);
    }
    k_lnlast<<<CW, 256, 0, stream>>>(f_xc, b_yfin, lnfg, lnfb, c, CW);
  }

  // ---- lm_head: logits = yfinal @ emb^T (emb already [N][K]), scatter to (B,S,V) ----
  k_mgemm<128><<<dim3(NWc/128, Vc/128), 256, 0, stream>>>(
      b_yfin, b_embbf, nullptr, nullptr, nullptr,
      NWc, Vc, Dm, GF_SCAT, out);
}

// Round 3
// 4841.427 us; speedup vs baseline: 3.5664x; 1.3590x over previous
//
#include <hip/hip_runtime.h>
#include <hip/hip_bf16.h>

// ---------------- architecture constants ----------------
namespace {
constexpr int Bz  = 4;      // batch
constexpr int Sq  = 256;    // seq len
constexpr int Dm  = 512;    // d_model
constexpr int NHd = 8;      // heads
constexpr int Tw  = 65;     // window (1 ssm + 64 input)
constexpr int DFFc= 2048;   // ffn hidden
constexpr int Vc  = 32000;  // vocab
constexpr int DKc = 64;     // pool key dim
constexpr int DIc = 1024;   // ssm d_inner
constexpr int DSc = 16;     // ssm d_state
constexpr int NWc = Bz*Sq;  // 1024 windows
constexpr int NTAB= 1089;   // shared layer-1 qkv table rows: 1024 tok + 64 ssm + 1 zero

constexpr int GF_BIAS = 1;
constexpr int GF_GELU = 2;
constexpr int GF_RES  = 4;
constexpr int GF_SCAT = 8;
constexpr int GF_OBF  = 16;   // bf16 output
}

typedef __hip_bfloat16 bf16;

__device__ __forceinline__ void async16(const void* g, void* l) {
  __builtin_amdgcn_global_load_lds(
      (const __attribute__((address_space(1))) unsigned int*)g,
      (__attribute__((address_space(3))) unsigned int*)l, 16, 0, 0);
}
__device__ __forceinline__ int imin(int a, int b) { return a < b ? a : b; }

// ---------------- utility kernels ----------------
__global__ __launch_bounds__(256) void k_zero(float* p, int n) {
  int i = blockIdx.x*256 + threadIdx.x;
  if (i < n) p[i] = 0.f;
}

__global__ __launch_bounds__(256) void k_gather(const int* ids, const float* emb, float* emb_seq) {
  int e = blockIdx.x*256 + threadIdx.x;          // Bz*Sq*Dm total
  int d  = e & (Dm-1);
  int bs = e >> 9;                               // b*Sq + s
  emb_seq[e] = emb[(size_t)ids[bs]*Dm + d];
}

// fp32 -> bf16 convert, 4 elems/thread
__global__ __launch_bounds__(256) void k_cvt4(const float* in, bf16* out, int n4) {
  int i = blockIdx.x*256 + threadIdx.x;
  if (i < n4) {
    float4 v = ((const float4*)in)[i];
    bf16* o = out + (size_t)i*4;
    o[0] = (bf16)v.x; o[1] = (bf16)v.y; o[2] = (bf16)v.z; o[3] = (bf16)v.w;
  }
}

// transpose+convert: out[n*K+k] = bf16(in[k*N+n]); K,N multiples of 32
__global__ __launch_bounds__(256) void k_wconv_t(const float* in, bf16* out, int K, int N) {
  __shared__ float t[32][33];
  int k0 = blockIdx.x*32, n0 = blockIdx.y*32;
  int tx = threadIdx.x & 31, ty = threadIdx.x >> 5;  // 32 x 8
  #pragma unroll
  for (int i = 0; i < 4; i++)
    t[ty + i*8][tx] = in[(size_t)(k0 + ty + i*8)*N + n0 + tx];
  __syncthreads();
  #pragma unroll
  for (int i = 0; i < 4; i++)
    out[(size_t)(n0 + ty + i*8)*K + k0 + tx] = (bf16)t[tx][ty + i*8];
}

__global__ __launch_bounds__(256) void k_uvec(const float* pool_wk, const float* pool_q, float* u) {
  int d = blockIdx.x*256 + threadIdx.x;
  if (d < Dm) {
    float acc = 0.f;
    for (int e = 0; e < DKc; e++) acc += pool_wk[d*DKc + e]*pool_q[e];
    u[d] = acc;
  }
}

// Precompute pool softmax partials over the 64 input slots for each write step.
__global__ __launch_bounds__(256) void k_poolpre(const float* emb_seq, const float* u,
                                                 float* Pres, float* Zres, float* Mres) {
  int kk = blockIdx.x / Bz + 1;   // 1..15
  int b  = blockIdx.x % Bz;
  int t  = kk*16;
  __shared__ float sj[64];
  __shared__ float ej[64];
  __shared__ float sM;
  int tid = threadIdx.x;
  if (tid < 64) {
    int j = tid + 1;              // window pos 1..64
    int idx = t - 64 + j;
    float s = 0.f;
    if (idx >= 0) {
      const float* row = emb_seq + ((size_t)b*Sq + idx)*Dm;
      float acc = 0.f;
      for (int d = 0; d < Dm; d++) acc += row[d]*u[d];
      s = acc*0.125f;
    }
    sj[tid] = s;
  }
  __syncthreads();
  if (tid == 0) {
    float m = -1e30f;
    for (int j = 0; j < 64; j++) m = fmaxf(m, sj[j]);
    sM = m;
  }
  __syncthreads();
  if (tid < 64) ej[tid] = expf(sj[tid] - sM);
  __syncthreads();
  if (tid == 0) {
    float z = 0.f;
    for (int j = 0; j < 64; j++) z += ej[j];
    Zres[kk*Bz + b] = z;
    Mres[kk*Bz + b] = sM;
  }
  __syncthreads();
  for (int d = tid; d < Dm; d += 256) {
    float acc = 0.f;
    for (int j = 1; j <= 64; j++) {
      int idx = t - 64 + j;
      if (idx >= 0) acc += ej[j-1]*emb_seq[((size_t)b*Sq + idx)*Dm + d];
    }
    Pres[((size_t)kk*Bz + b)*Dm + d] = acc;
  }
}

// ---------------- phase 1: sequential SSM (write steps only) ----------------
__global__ __launch_bounds__(256) void k_ssm_xz(const float* win, const float* ssm_vec,
                                                const float* Pres, const float* Zres, const float* Mres,
                                                const float* u, const float* xb, float* pooled,
                                                float* x1buf, float* zbuf, int kk, int layer) {
  int jg = blockIdx.x;       // 0..31
  int b  = blockIdx.y;
  int tid = threadIdx.x;
  __shared__ float xin[Dm];
  __shared__ float red[256];
  __shared__ float r2[4][64];
  if (layer == 0) {
    const float* sv = ssm_vec + ((size_t)(kk-1)*Bz + b)*Dm;
    float p = 0.f;
    for (int i = tid; i < Dm; i += 256) p += sv[i]*u[i];
    red[tid] = p; __syncthreads();
    for (int s = 128; s > 0; s >>= 1) { if (tid < s) red[tid] += red[tid+s]; __syncthreads(); }
    float s0  = red[0]*0.125f;
    float e0  = expf(s0 - Mres[kk*Bz + b]);
    float inv = 1.f/(e0 + Zres[kk*Bz + b]);
    const float* Pr = Pres + ((size_t)kk*Bz + b)*Dm;
    for (int i = tid; i < Dm; i += 256) {
      float val = (e0*sv[i] + Pr[i])*inv;
      xin[i] = val;
      if (jg == 0) pooled[b*Dm + i] = val;
    }
  } else {
    for (int i = tid; i < Dm; i += 256) xin[i] = xb[b*Dm + i];
  }
  __syncthreads();
  int ks = tid >> 6, jl = tid & 63;
  int j  = jg*64 + jl;                  // 0..2047
  const float* w = win + j;
  float acc = 0.f;
  int k0 = ks*128;
  #pragma unroll 8
  for (int k = k0; k < k0 + 128; k++) acc += xin[k]*w[(size_t)k*(2*DIc)];
  r2[ks][jl] = acc; __syncthreads();
  if (tid < 64) {
    int jj = jg*64 + tid;
    float v = r2[0][tid] + r2[1][tid] + r2[2][tid] + r2[3][tid];
    if (jj < DIc) x1buf[b*DIc + jj] = v;
    else          zbuf[b*DIc + (jj - DIc)] = v;
  }
}

__global__ __launch_bounds__(256) void k_ssm_proj(const float* wdt, const float* bdt,
                                                  const float* wB, const float* wC,
                                                  const float* x1buf, float* dtbuf,
                                                  float* Bmbuf, float* Cmbuf) {
  int bx = blockIdx.x;       // 0..16
  int b  = blockIdx.y;
  int tid = threadIdx.x;
  __shared__ float x1[DIc];
  __shared__ float r2[4][64];
  __shared__ float r3[8][32];
  for (int i = tid; i < DIc; i += 256) x1[i] = x1buf[b*DIc + i];
  __syncthreads();
  if (bx < 16) {
    int ks = tid >> 6, jl = tid & 63;
    int j = bx*64 + jl;
    const float* w = wdt + j;
    float acc = 0.f;
    int k0 = ks*256;
    #pragma unroll 8
    for (int k = k0; k < k0 + 256; k++) acc += x1[k]*w[(size_t)k*DIc];
    r2[ks][jl] = acc; __syncthreads();
    if (tid < 64) {
      int jj = bx*64 + tid;
      float v = r2[0][tid] + r2[1][tid] + r2[2][tid] + r2[3][tid] + bdt[jj];
      dtbuf[b*DIc + jj] = fmaxf(v, 0.f) + log1pf(expf(-fabsf(v)));   // stable softplus
    }
  } else {
    int ks = tid >> 5, jl = tid & 31;
    int s  = jl & 15;
    const float* w = (jl < 16 ? wB : wC) + s;
    float acc = 0.f;
    int k0 = ks*128;
    #pragma unroll 8
    for (int k = k0; k < k0 + 128; k++) acc += x1[k]*w[(size_t)k*DSc];
    r3[ks][jl] = acc; __syncthreads();
    if (tid < 32) {
      float v = 0.f;
      for (int q = 0; q < 8; q++) v += r3[q][tid];
      if (tid < 16) Bmbuf[b*DSc + tid] = v;
      else          Cmbuf[b*DSc + (tid - 16)] = v;
    }
  }
}

// fused: h' = exp(dt*A)h + dt*Bm*x1; y = (h'.Cm + D*x1)*silu(z); dst = xbase + y @ wout
// h is ping-ponged (hin read-only, hout written by jg==0 blocks only -> no RMW race)
__global__ __launch_bounds__(256) void k_ssm_hyout(
    const float* Alog, const float* ssmD, const float* dtbuf, const float* x1buf,
    const float* zbuf, const float* Bmbuf, const float* Cmbuf,
    const float* hin, float* hout,
    const float* wout, const float* xbase, float* dst) {
  int jg = blockIdx.x;       // 0..7
  int b  = blockIdx.y;
  int tid = threadIdx.x;
  __shared__ float y[DIc];
  __shared__ float r2[4][64];
  for (int d0 = tid; d0 < DIc; d0 += 256) {
    int g = b*DIc + d0;
    float dt = dtbuf[g];
    float x1 = x1buf[g];
    float z  = zbuf[g];
    float sil = z / (1.f + expf(-z));
    const float* hi = hin + (size_t)g*DSc;
    float*       ho = hout + (size_t)g*DSc;
    const float* Ar = Alog + (size_t)d0*DSc;
    float acc = 0.f;
    #pragma unroll
    for (int s = 0; s < DSc; s++) {
      float hn = expf(dt*-expf(Ar[s]))*hi[s] + dt*Bmbuf[b*DSc + s]*x1;
      if (jg == 0) ho[s] = hn;
      acc += hn*Cmbuf[b*DSc + s];
    }
    y[d0] = (acc + ssmD[d0]*x1)*sil;
  }
  __syncthreads();
  int ks = tid >> 6, jl = tid & 63;
  int j = jg*64 + jl;
  const float* w = wout + j;
  float acc = 0.f;
  int k0 = ks*256;
  #pragma unroll 8
  for (int k = k0; k < k0 + 256; k++) acc += y[k]*w[(size_t)k*Dm];
  r2[ks][jl] = acc; __syncthreads();
  if (tid < 64) {
    int jj = jg*64 + tid;
    dst[b*Dm + jj] = xbase[b*Dm + jj] + r2[0][tid] + r2[1][tid] + r2[2][tid] + r2[3][tid];
  }
}

// ---------------- phase 2 ----------------
// residual-stream window build (fp32)
__global__ __launch_bounds__(256) void k_build(const float* emb_seq, const float* ssm_vec,
                                               float* xc, int c, int CW) {
  int e = blockIdx.x*256 + threadIdx.x;   // RC*Dm total
  int d = e & (Dm-1);
  int r = e >> 9;
  int wc = r / Tw, p = r % Tw;
  int w  = c*CW + wc;
  int t  = w >> 2, b = w & 3;
  float val;
  if (p == 0) {
    int kused = (t == 0) ? 0 : ((t-1) >> 4);
    val = ssm_vec[((size_t)kused*Bz + b)*Dm + d];
  } else {
    int idx = t - 64 + p;
    val = (idx >= 0) ? emb_seq[((size_t)b*Sq + idx)*Dm + d] : 0.f;
  }
  xc[e] = val;
}

// LN: fp32 in -> bf16 out (one block per row)
__global__ __launch_bounds__(256) void k_ln(const float* src, bf16* dst,
                                            const float* g, const float* bb) {
  int r = blockIdx.x;
  int tid = threadIdx.x;
  const float* x = src + (size_t)r*Dm;
  float v0 = x[tid], v1 = x[tid + 256];
  __shared__ float rs[256], rq[256];
  rs[tid] = v0 + v1; rq[tid] = v0*v0 + v1*v1;
  __syncthreads();
  for (int s = 128; s > 0; s >>= 1) {
    if (tid < s) { rs[tid] += rs[tid+s]; rq[tid] += rq[tid+s]; }
    __syncthreads();
  }
  float mu   = rs[0]*(1.f/Dm);
  float var  = rq[0]*(1.f/Dm) - mu*mu;
  float rstd = rsqrtf(var + 1e-5f);
  bf16* y = dst + (size_t)r*Dm;
  y[tid]       = (bf16)((v0 - mu)*rstd*g[tid]       + bb[tid]);
  y[tid + 256] = (bf16)((v1 - mu)*rstd*g[tid + 256] + bb[tid + 256]);
}

// build the shared layer-1 LN1 table: rows 0..1023 tokens, 1024..1087 ssm slots, 1088 zero-row
__global__ __launch_bounds__(256) void k_ln_tab(const float* emb_seq, const float* ssm_vec,
                                                bf16* atab, const float* g, const float* bb) {
  int r = blockIdx.x;
  int tid = threadIdx.x;
  float v0, v1;
  if (r < 1024) {
    const float* x = emb_seq + (size_t)r*Dm;
    v0 = x[tid]; v1 = x[tid + 256];
  } else if (r < 1088) {
    int q = r - 1024;                 // kk*4 + b
    const float* x = ssm_vec + (size_t)q*Dm;
    v0 = x[tid]; v1 = x[tid + 256];
  } else {
    v0 = 0.f; v1 = 0.f;
  }
  __shared__ float rs[256], rq[256];
  rs[tid] = v0 + v1; rq[tid] = v0*v0 + v1*v1;
  __syncthreads();
  for (int s = 128; s > 0; s >>= 1) {
    if (tid < s) { rs[tid] += rs[tid+s]; rq[tid] += rq[tid+s]; }
    __syncthreads();
  }
  float mu   = rs[0]*(1.f/Dm);
  float var  = rq[0]*(1.f/Dm) - mu*mu;
  float rstd = rsqrtf(var + 1e-5f);
  bf16* y = atab + (size_t)r*Dm;
  y[tid]       = (bf16)((v0 - mu)*rstd*g[tid]       + bb[tid]);
  y[tid + 256] = (bf16)((v1 - mu)*rstd*g[tid + 256] + bb[tid + 256]);
}

// gather last-row activations (hbf bf16 -> hq_all; xc fp32 -> xl_all)
__global__ __launch_bounds__(256) void k_glast(const bf16* hbf, const float* xc,
                                               bf16* hq_all, float* xl_all, int c, int CW) {
  int wc = blockIdx.x;
  int w  = c*CW + wc;
  int tid = threadIdx.x;
  size_t rsrc = ((size_t)wc*Tw + (Tw-1))*Dm;
  size_t rdst = (size_t)w*Dm;
  hq_all[rdst + tid]       = hbf[rsrc + tid];
  hq_all[rdst + tid + 256] = hbf[rsrc + tid + 256];
  xl_all[rdst + tid]       = xc[rsrc + tid];
  xl_all[rdst + tid + 256] = xc[rsrc + tid + 256];
}

// ---------------- bf16 MFMA GEMM (m97 recipe) ----------------
template<int TN>
__global__ __launch_bounds__(256) void k_mgemm(
    const bf16* __restrict__ A, const bf16* __restrict__ Bt, void* __restrict__ C,
    const float* __restrict__ bias, const float* __restrict__ resid,
    int M, int N, int K, int flags, float* __restrict__ outbase) {
  constexpr int TM = 128, BK = 32;
  constexpr int WN = TN/2, NF = WN/16;
  __shared__ bf16 As[TM*BK];
  __shared__ bf16 Bs[TN*BK];
  const int tid  = threadIdx.x;
  const int wave = tid >> 6, lane = tid & 63;
  const int m0 = blockIdx.x*TM, n0 = blockIdx.y*TN;
  const int wm = (wave>>1)*64, wn = (wave&1)*WN;
  using frag = __attribute__((ext_vector_type(8))) short;
  using f4   = __attribute__((ext_vector_type(4))) float;
  f4 acc[4][NF];
  #pragma unroll
  for (int i = 0; i < 4; i++)
    #pragma unroll
    for (int j = 0; j < NF; j++) acc[i][j] = (f4){0.f, 0.f, 0.f, 0.f};

  const int srow = lane >> 2;
  const int scol = (lane & 3)*8;
  const int am0 = imin(m0 + wave*32 + srow,      M-1);
  const int am1 = imin(m0 + wave*32 + 16 + srow, M-1);
  const bf16* gA0 = A + (size_t)am0*K + scol;
  const bf16* gA1 = A + (size_t)am1*K + scol;
  bf16* lA0 = As + wave*1024;
  bf16* lA1 = As + wave*1024 + 512;
  const bf16 *gB0, *gB1 = nullptr;
  bf16 *lB0, *lB1 = nullptr;
  if (TN == 128) {
    gB0 = Bt + (size_t)imin(n0 + wave*32 + srow,      N-1)*K + scol;
    gB1 = Bt + (size_t)imin(n0 + wave*32 + 16 + srow, N-1)*K + scol;
    lB0 = Bs + wave*1024;
    lB1 = Bs + wave*1024 + 512;
  } else {
    gB0 = Bt + (size_t)imin(n0 + wave*16 + srow, N-1)*K + scol;
    lB0 = Bs + wave*512;
  }

  const int fr = lane & 15;
  const int q8 = (lane >> 4)*8;
  for (int k0 = 0; k0 < K; k0 += BK) {
    async16(gA0 + k0, lA0);
    async16(gA1 + k0, lA1);
    async16(gB0 + k0, lB0);
    if (TN == 128) async16(gB1 + k0, lB1);
    __syncthreads();
    frag af[4], bfr[NF];
    #pragma unroll
    for (int i = 0; i < 4; i++)
      af[i] = *(const frag*)(As + (wm + i*16 + fr)*BK + q8);
    #pragma unroll
    for (int j = 0; j < NF; j++)
      bfr[j] = *(const frag*)(Bs + (wn + j*16 + fr)*BK + q8);
    #pragma unroll
    for (int i = 0; i < 4; i++)
      #pragma unroll
      for (int j = 0; j < NF; j++)
        acc[i][j] = __builtin_amdgcn_mfma_f32_16x16x32_bf16(af[i], bfr[j], acc[i][j], 0, 0, 0);
    __syncthreads();
  }

  const int col = lane & 15, r0 = (lane >> 4)*4;
  #pragma unroll
  for (int i = 0; i < 4; i++) {
    #pragma unroll
    for (int j = 0; j < NF; j++) {
      #pragma unroll
      for (int r = 0; r < 4; r++) {
        int gm = m0 + wm + i*16 + r0 + r;
        int gn = n0 + wn + j*16 + col;
        if (gm >= M) continue;
        float v = acc[i][j][r];
        if (flags & GF_BIAS) v += bias[gn];
        if (flags & GF_GELU) {
          float x  = v;
          float uu = 0.7978845608028654f*(x + 0.044715f*x*x*x);
          float th = 1.f - 2.f/(expf(2.f*uu) + 1.f);
          v = 0.5f*x*(1.f + th);
        }
        if (flags & GF_RES) v += resid[(size_t)gm*N + gn];
        if (flags & GF_SCAT) {
          int t = gm >> 2, b = gm & 3;
          outbase[((size_t)b*Sq + t)*Vc + gn] = v;
        } else if (flags & GF_OBF) {
          ((bf16*)C)[(size_t)gm*N + gn] = (bf16)v;
        } else {
          ((float*)C)[(size_t)gm*N + gn] = v;
        }
      }
    }
  }
}

// layer-1 attention with table indirection: per (window, head)
__global__ __launch_bounds__(256) void k_attn1(const bf16* tab, bf16* attno, int c, int CW) {
  __shared__ float qs[Tw][68];   // q, later reused for v
  __shared__ float ksh[Tw][68];
  __shared__ float ss[Tw][68];
  __shared__ int rowi[Tw];
  int wc = blockIdx.x >> 3;
  int h  = blockIdx.x & 7;
  int tid = threadIdx.x;
  int w = c*CW + wc;
  int t = w >> 2, b = w & 3;
  if (tid < Tw) {
    int p = tid, r;
    if (p == 0) {
      int kused = (t == 0) ? 0 : ((t-1) >> 4);
      r = 1024 + kused*Bz + b;
    } else {
      int idx = t - 64 + p;
      r = (idx >= 0) ? (b*Sq + idx) : 1088;
    }
    rowi[p] = r;
  }
  __syncthreads();
  for (int e = tid; e < Tw*32; e += 256) {
    int p = e >> 5, d2 = (e & 31)*2;
    const bf16* base = tab + (size_t)rowi[p]*(3*Dm) + h*64 + d2;
    qs[p][d2]    = __bfloat162float(base[0]);
    qs[p][d2+1]  = __bfloat162float(base[1]);
    ksh[p][d2]   = __bfloat162float(base[Dm]);
    ksh[p][d2+1] = __bfloat162float(base[Dm+1]);
  }
  __syncthreads();
  for (int e = tid; e < Tw*Tw; e += 256) {
    int i = e / Tw, j = e % Tw;
    float v;
    if (j > i) v = -1e9f;
    else {
      float a0 = 0.f, a1 = 0.f;
      #pragma unroll 8
      for (int d = 0; d < 64; d += 2) { a0 += qs[i][d]*ksh[j][d]; a1 += qs[i][d+1]*ksh[j][d+1]; }
      v = (a0 + a1)*0.125f;
    }
    ss[i][j] = v;
  }
  __syncthreads();
  if (tid < Tw) {
    int i = tid;
    float m = -1e30f;
    for (int j = 0; j < Tw; j++) m = fmaxf(m, ss[i][j]);
    float sum = 0.f;
    for (int j = 0; j < Tw; j++) { float eL = expf(ss[i][j] - m); ss[i][j] = eL; sum += eL; }
    float inv = 1.f/sum;
    for (int j = 0; j < Tw; j++) ss[i][j] *= inv;
  }
  __syncthreads();
  // stage V into qs
  for (int e = tid; e < Tw*32; e += 256) {
    int p = e >> 5, d2 = (e & 31)*2;
    const bf16* base = tab + (size_t)rowi[p]*(3*Dm) + 2*Dm + h*64 + d2;
    qs[p][d2]   = __bfloat162float(base[0]);
    qs[p][d2+1] = __bfloat162float(base[1]);
  }
  __syncthreads();
  size_t row0 = (size_t)wc*Tw;
  for (int e = tid; e < Tw*64; e += 256) {
    int i = e >> 6, d = e & 63;
    float acc = 0.f;
    for (int j = 0; j <= i; j++) acc += ss[i][j]*qs[j][d];
    attno[(row0 + i)*Dm + h*64 + d] = (bf16)acc;
  }
}

// layer-2 attention, last query row only: per (window, head)
__global__ __launch_bounds__(128) void k_attn2(const bf16* q2, const bf16* kvbuf,
                                               bf16* o2_all, int c, int CW) {
  __shared__ float qv[64];
  __shared__ float ps[Tw];
  __shared__ float red[2];
  int wc = blockIdx.x >> 3;
  int h  = blockIdx.x & 7;
  int tid = threadIdx.x;
  int w = c*CW + wc;
  if (tid < 64) qv[tid] = __bfloat162float(q2[(size_t)wc*Dm + h*64 + tid]);
  __syncthreads();
  if (tid < Tw) {
    const bf16* kr = kvbuf + ((size_t)wc*Tw + tid)*(2*Dm) + h*64;
    float acc = 0.f;
    #pragma unroll 8
    for (int d = 0; d < 64; d++) acc += qv[d]*__bfloat162float(kr[d]);
    ps[tid] = acc*0.125f;
  }
  __syncthreads();
  if (tid == 0) {
    float m = -1e30f;
    for (int j = 0; j < Tw; j++) m = fmaxf(m, ps[j]);
    red[0] = m;
  }
  __syncthreads();
  if (tid < Tw) ps[tid] = expf(ps[tid] - red[0]);
  __syncthreads();
  if (tid == 0) {
    float z = 0.f;
    for (int j = 0; j < Tw; j++) z += ps[j];
    red[1] = 1.f/z;
  }
  __syncthreads();
  if (tid < 64) {
    float inv = red[1];
    float acc = 0.f;
    for (int j = 0; j < Tw; j++) {
      const bf16* vr = kvbuf + ((size_t)wc*Tw + j)*(2*Dm) + Dm + h*64;
      acc += ps[j]*__bfloat162float(vr[tid]);
    }
    o2_all[(size_t)w*Dm + h*64 + tid] = (bf16)(acc*inv);
  }
}

// ---------------- host launch ----------------
extern "C" void kernel_launch(void* const* d_in, const int* in_sizes, int n_in,
                              void* d_out, int out_size, void* d_ws, size_t ws_size,
                              hipStream_t stream) {
  const int*   ids    = (const int*)  d_in[0];
  const float* emb    = (const float*)d_in[1];
  const float* ln1g   = (const float*)d_in[2];
  const float* ln1b   = (const float*)d_in[3];
  const float* wqkv   = (const float*)d_in[4];
  const float* wo     = (const float*)d_in[5];
  const float* ln2g   = (const float*)d_in[6];
  const float* ln2b   = (const float*)d_in[7];
  const float* w1     = (const float*)d_in[8];
  const float* b1     = (const float*)d_in[9];
  const float* w2     = (const float*)d_in[10];
  const float* b2     = (const float*)d_in[11];
  const float* lnfg   = (const float*)d_in[12];
  const float* lnfb   = (const float*)d_in[13];
  const float* poolq  = (const float*)d_in[14];
  const float* poolwk = (const float*)d_in[15];
  const float* swin   = (const float*)d_in[16];
  const float* swdt   = (const float*)d_in[17];
  const float* sbdt   = (const float*)d_in[18];
  const float* sAlog  = (const float*)d_in[19];
  const float* swB    = (const float*)d_in[20];
  const float* swC    = (const float*)d_in[21];
  const float* sDd    = (const float*)d_in[22];
  const float* swout  = (const float*)d_in[23];
  float* out = (float*)d_out;
  char*  wsb = (char*)d_ws;

  size_t off = 0;
  auto alloc = [&](size_t bytes) {
    size_t o = off;
    off += (bytes + 255) & ~(size_t)255;
    return o;
  };
  size_t o_ssmvec = alloc((size_t)16*Bz*Dm*4);            // fp32; adjacent to h ping-pong
  size_t o_h      = alloc((size_t)2*2*Bz*DIc*DSc*4);      // [parity][layer][B][DI][DS]
  size_t o_embseq = alloc((size_t)Bz*Sq*Dm*4);
  size_t o_u      = alloc((size_t)Dm*4);
  size_t o_P      = alloc((size_t)16*Bz*Dm*4);
  size_t o_Z      = alloc((size_t)16*Bz*4);
  size_t o_M      = alloc((size_t)16*Bz*4);
  size_t o_pool   = alloc((size_t)Bz*Dm*4);
  size_t o_xb     = alloc((size_t)Bz*Dm*4);
  size_t o_x1     = alloc((size_t)Bz*DIc*4);
  size_t o_zb     = alloc((size_t)Bz*DIc*4);
  size_t o_dt     = alloc((size_t)Bz*DIc*4);
  size_t o_Bm     = alloc((size_t)Bz*DSc*4);
  size_t o_Cm     = alloc((size_t)Bz*DSc*4);
  size_t o_yfin   = alloc((size_t)NWc*Dm*2);              // bf16
  size_t o_wqkvT  = alloc((size_t)2*3*Dm*Dm*2);
  size_t o_woT    = alloc((size_t)2*Dm*Dm*2);
  size_t o_w1T    = alloc((size_t)2*DFFc*Dm*2);
  size_t o_w2T    = alloc((size_t)2*Dm*DFFc*2);
  size_t o_embbf  = alloc((size_t)Vc*Dm*2);
  size_t o_atab   = alloc((size_t)1152*Dm*2);             // LN1(l0) table, bf16
  size_t o_qtab   = alloc((size_t)1152*3*Dm*2);           // shared layer-1 qkv table
  size_t o_hq     = alloc((size_t)NWc*Dm*2);              // last-row ln1(l1) (bf16)
  size_t o_o2     = alloc((size_t)NWc*Dm*2);              // last-row attn2 out (bf16)
  size_t o_xl     = alloc((size_t)NWc*Dm*4);              // last-row residual (fp32)
  size_t o_xl2    = alloc((size_t)NWc*Dm*4);
  size_t o_hbf2   = alloc((size_t)NWc*Dm*2);
  size_t o_ffh2   = alloc((size_t)NWc*DFFc*2);
  size_t o_q2m    = alloc((size_t)128*Dm*2);              // per-chunk q-last (bf16)

  // per-chunk buffers: xc fp32(2048B/row) + hbf(1024) + ffh(4096) + kv(2048) = 9216 B/row
  int CW = 128;
  while (CW > 16) {
    size_t need = off + (size_t)CW*Tw*9216 + 8192;
    if (need <= ws_size) break;
    CW >>= 1;
  }
  int RC = CW*Tw;
  size_t o_xc  = alloc((size_t)RC*Dm*4);
  size_t o_hbf = alloc((size_t)RC*Dm*2);
  size_t o_ffh = alloc((size_t)RC*DFFc*2);
  size_t o_kv  = alloc((size_t)RC*2*Dm*2);
  int NCH = NWc/CW;

  float* f_ssmvec = (float*)(wsb + o_ssmvec);
  float* f_h      = (float*)(wsb + o_h);
  float* f_embseq = (float*)(wsb + o_embseq);
  bf16*  b_yfin   = (bf16*) (wsb + o_yfin);
  bf16*  b_wqkvT  = (bf16*) (wsb + o_wqkvT);
  bf16*  b_woT    = (bf16*) (wsb + o_woT);
  bf16*  b_w1T    = (bf16*) (wsb + o_w1T);
  bf16*  b_w2T    = (bf16*) (wsb + o_w2T);
  bf16*  b_embbf  = (bf16*) (wsb + o_embbf);
  bf16*  b_atab   = (bf16*) (wsb + o_atab);
  bf16*  b_qtab   = (bf16*) (wsb + o_qtab);
  bf16*  b_hq     = (bf16*) (wsb + o_hq);
  bf16*  b_o2     = (bf16*) (wsb + o_o2);
  float* f_xl     = (float*)(wsb + o_xl);
  float* f_xl2    = (float*)(wsb + o_xl2);
  bf16*  b_hbf2   = (bf16*) (wsb + o_hbf2);
  bf16*  b_ffh2   = (bf16*) (wsb + o_ffh2);
  bf16*  b_q2     = (bf16*) (wsb + o_q2m);
  float* f_xc     = (float*)(wsb + o_xc);
  bf16*  b_hbf    = (bf16*) (wsb + o_hbf);
  bf16*  b_ffh    = (bf16*) (wsb + o_ffh);
  bf16*  b_kv     = (bf16*) (wsb + o_kv);

  const size_t hlay = (size_t)Bz*DIc*DSc;                 // floats per layer-state
  const size_t hpar = 2*hlay;                             // floats per parity

  // ---- phase 0 ----
  int nz = 16*Bz*Dm + (int)hpar;                          // ssmvec + h parity-0 (contiguous)
  k_zero<<<(nz + 255)/256, 256, 0, stream>>>(f_ssmvec, nz);
  k_gather<<<(Bz*Sq*Dm)/256, 256, 0, stream>>>(ids, emb, f_embseq);
  k_uvec<<<2, 256, 0, stream>>>(poolwk, poolq, (float*)(wsb + o_u));
  k_poolpre<<<15*Bz, 256, 0, stream>>>(f_embseq, (float*)(wsb + o_u),
                                       (float*)(wsb + o_P), (float*)(wsb + o_Z),
                                       (float*)(wsb + o_M));
  for (int l = 0; l < 2; l++) {
    k_wconv_t<<<dim3(Dm/32, 3*Dm/32), 256, 0, stream>>>(
        wqkv + (size_t)l*Dm*3*Dm, b_wqkvT + (size_t)l*3*Dm*Dm, Dm, 3*Dm);
    k_wconv_t<<<dim3(Dm/32, Dm/32), 256, 0, stream>>>(
        wo + (size_t)l*Dm*Dm, b_woT + (size_t)l*Dm*Dm, Dm, Dm);
    k_wconv_t<<<dim3(Dm/32, DFFc/32), 256, 0, stream>>>(
        w1 + (size_t)l*Dm*DFFc, b_w1T + (size_t)l*DFFc*Dm, Dm, DFFc);
    k_wconv_t<<<dim3(DFFc/32, Dm/32), 256, 0, stream>>>(
        w2 + (size_t)l*DFFc*Dm, b_w2T + (size_t)l*Dm*DFFc, DFFc, Dm);
  }
  k_cvt4<<<(Vc*Dm/4 + 255)/256, 256, 0, stream>>>(emb, b_embbf, Vc*Dm/4);

  // ---- phase 1: 15 sequential SSM write steps (3 kernels per layer-step) ----
  for (int kk = 1; kk <= 15; kk++) {
    int pin = (kk-1) & 1, pout = kk & 1;
    for (int l = 0; l < 2; l++) {
      k_ssm_xz<<<dim3(32, Bz), 256, 0, stream>>>(
          swin + (size_t)l*Dm*2*DIc, f_ssmvec,
          (float*)(wsb + o_P), (float*)(wsb + o_Z), (float*)(wsb + o_M),
          (float*)(wsb + o_u), (float*)(wsb + o_xb), (float*)(wsb + o_pool),
          (float*)(wsb + o_x1), (float*)(wsb + o_zb), kk, l);
      k_ssm_proj<<<dim3(17, Bz), 256, 0, stream>>>(
          swdt + (size_t)l*DIc*DIc, sbdt + (size_t)l*DIc,
          swB + (size_t)l*DIc*DSc, swC + (size_t)l*DIc*DSc,
          (float*)(wsb + o_x1), (float*)(wsb + o_dt),
          (float*)(wsb + o_Bm), (float*)(wsb + o_Cm));
      k_ssm_hyout<<<dim3(8, Bz), 256, 0, stream>>>(
          sAlog + (size_t)l*DIc*DSc, sDd + (size_t)l*DIc,
          (float*)(wsb + o_dt), (float*)(wsb + o_x1), (float*)(wsb + o_zb),
          (float*)(wsb + o_Bm), (float*)(wsb + o_Cm),
          f_h + pin*hpar + l*hlay, f_h + pout*hpar + l*hlay,
          swout + (size_t)l*DIc*Dm,
          (l == 0 ? (float*)(wsb + o_pool) : (float*)(wsb + o_xb)),
          (l == 0 ? (float*)(wsb + o_xb)   : f_ssmvec + (size_t)kk*Bz*Dm));
    }
  }

  // ---- shared layer-1 qkv table (after phase 1: needs ssm vectors) ----
  k_ln_tab<<<NTAB, 256, 0, stream>>>(f_embseq, f_ssmvec, b_atab, ln1g, ln1b);
  k_mgemm<128><<<dim3((NTAB+127)/128, 3*Dm/128), 256, 0, stream>>>(
      b_atab, b_wqkvT, b_qtab, nullptr, nullptr, NTAB, 3*Dm, Dm, GF_OBF, nullptr);

  // ---- phase 2: per-chunk ----
  int mt = (RC + 127)/128;
  for (int c = 0; c < NCH; c++) {
    k_build<<<RC*2, 256, 0, stream>>>(f_embseq, f_ssmvec, f_xc, c, CW);
    // layer 1 (l=0): attn from shared table, then WO + FFN (full rows)
    k_attn1<<<CW*NHd, 256, 0, stream>>>(b_qtab, b_hbf, c, CW);
    k_mgemm<64><<<dim3(mt, Dm/64), 256, 0, stream>>>(
        b_hbf, b_woT, f_xc, nullptr, f_xc, RC, Dm, Dm, GF_RES, nullptr);
    k_ln<<<RC, 256, 0, stream>>>(f_xc, b_hbf, ln2g, ln2b);
    k_mgemm<128><<<dim3(mt, DFFc/128), 256, 0, stream>>>(
        b_hbf, b_w1T, b_ffh, b1, nullptr, RC, DFFc, Dm, GF_BIAS|GF_GELU|GF_OBF, nullptr);
    k_mgemm<64><<<dim3(mt, Dm/64), 256, 0, stream>>>(
        b_ffh, b_w2T, f_xc, b2, f_xc, RC, Dm, DFFc, GF_BIAS|GF_RES, nullptr);
    // layer 2 (l=1): LN1 + K,V full rows; Q/attn only last row
    k_ln<<<RC, 256, 0, stream>>>(f_xc, b_hbf, ln1g + Dm, ln1b + Dm);
    k_mgemm<128><<<dim3(mt, 2*Dm/128), 256, 0, stream>>>(
        b_hbf, b_wqkvT + (size_t)3*Dm*Dm + (size_t)512*Dm, b_kv,
        nullptr, nullptr, RC, 2*Dm, Dm, GF_OBF, nullptr);
    k_glast<<<CW, 256, 0, stream>>>(b_hbf, f_xc, b_hq, f_xl, c, CW);
    k_mgemm<64><<<dim3((CW+127)/128, Dm/64), 256, 0, stream>>>(
        b_hq + (size_t)c*CW*Dm, b_wqkvT + (size_t)3*Dm*Dm, b_q2,
        nullptr, nullptr, CW, Dm, Dm, GF_OBF, nullptr);
    k_attn2<<<CW*NHd, 128, 0, stream>>>(b_q2, b_kv, b_o2, c, CW);
  }

  // ---- layer-2 tail for all 1024 last rows ----
  int mt2 = NWc/128;
  k_mgemm<64><<<dim3(mt2, Dm/64), 256, 0, stream>>>(
      b_o2, b_woT + (size_t)Dm*Dm, f_xl2, nullptr, f_xl, NWc, Dm, Dm, GF_RES, nullptr);
  k_ln<<<NWc, 256, 0, stream>>>(f_xl2, b_hbf2, ln2g + Dm, ln2b + Dm);
  k_mgemm<128><<<dim3(mt2, DFFc/128), 256, 0, stream>>>(
      b_hbf2, b_w1T + (size_t)DFFc*Dm, b_ffh2, b1 + DFFc, nullptr,
      NWc, DFFc, Dm, GF_BIAS|GF_GELU|GF_OBF, nullptr);
  k_mgemm<64><<<dim3(mt2, Dm/64), 256, 0, stream>>>(
      b_ffh2, b_w2T + (size_t)Dm*DFFc, f_xl, b2 + Dm, f_xl2,
      NWc, Dm, DFFc, GF_BIAS|GF_RES, nullptr);
  k_ln<<<NWc, 256, 0, stream>>>(f_xl, b_yfin, lnfg, lnfb);

  // ---- lm_head: logits = yfin @ emb^T, scatter to (B,S,V) ----
  k_mgemm<128><<<dim3(NWc/128, Vc/128), 256, 0, stream>>>(
      b_yfin, b_embbf, nullptr, nullptr, nullptr,
      NWc, Vc, Dm, GF_SCAT, out);
}